// Round 17
// baseline (192.904 us; speedup 1.0000x reference)
//
#include <hip/hip_runtime.h>

typedef unsigned short u16;
typedef unsigned int   u32;

#define DCH  256
#define KCB  1024
#define HW   1024
#define NPOS 65536
#define GAPQ 578            // flag threshold: ceil((0.07+2^-12)*8192)

// ws layout (bytes)
#define ESQ_WS   0
#define IDX_WS   4096
#define FCNT_WS  266240
#define FLIST_WS 266304
#define ESQD_WS  528448ull             // double[1024] = 8 KB
#define XH_WS    1048576ull            // 65536*256 fp16 = 33.55 MB
#define EH_WS    34603008ull           // 1024*256 fp16 = 512 KB

using f32x4 = __attribute__((ext_vector_type(4))) float;
using f16x8 = __attribute__((ext_vector_type(8))) _Float16;

__device__ __forceinline__ u16 f2h(float x) {
    _Float16 h = (_Float16)x;
    return *reinterpret_cast<u16*>(&h);
}
__device__ __forceinline__ u32 umin2(u32 a, u32 b) { return a < b ? a : b; }
__device__ __forceinline__ u32 umax2(u32 a, u32 b) { return a > b ? a : b; }

__device__ __forceinline__ void gl_lds16(const void* g, void* l) {
    __builtin_amdgcn_global_load_lds(
        (const __attribute__((address_space(1))) void*)g,
        (__attribute__((address_space(3))) void*)l, 16, 0, 0);
}

// ---------------- fused prep: X transpose (2048 blocks) + E transpose (32) + esq (4)
__device__ __forceinline__ void transpose_slice(const float* __restrict__ src,
                                                u16* __restrict__ dst,
                                                int b, int pc, int cc, int tid) {
    __shared__ float Xs[32][260];     // pad 260 -> transpose reads conflict-free
    const int p0 = pc * 256;
    const int c0 = cc * 32;
    const size_t nbase = (size_t)b * 1024 + p0;
#pragma unroll
    for (int r = 0; r < 8; ++r) {
        int id4 = tid + 256 * r;            // float4 id over [32][64]
        int c = id4 >> 6;
        int q = id4 & 63;
        float4 v = *reinterpret_cast<const float4*>(
            src + (size_t)b * 262144 + (size_t)(c0 + c) * 1024 + p0 + q * 4);
        *reinterpret_cast<float4*>(&Xs[c][q * 4]) = v;
    }
    __syncthreads();
    const int p = tid;
#pragma unroll
    for (int dg = 0; dg < 4; ++dg) {
        u32 w0, w1, w2, w3;
        {
            float f0 = Xs[dg * 8 + 0][p], f1 = Xs[dg * 8 + 1][p];
            float f2 = Xs[dg * 8 + 2][p], f3 = Xs[dg * 8 + 3][p];
            float f4 = Xs[dg * 8 + 4][p], f5 = Xs[dg * 8 + 5][p];
            float f6 = Xs[dg * 8 + 6][p], f7 = Xs[dg * 8 + 7][p];
            w0 = (u32)f2h(f0) | ((u32)f2h(f1) << 16);
            w1 = (u32)f2h(f2) | ((u32)f2h(f3) << 16);
            w2 = (u32)f2h(f4) | ((u32)f2h(f5) << 16);
            w3 = (u32)f2h(f6) | ((u32)f2h(f7) << 16);
        }
        uint4 ov = {w0, w1, w2, w3};
        *reinterpret_cast<uint4*>(dst + (nbase + p) * 256 + c0 + dg * 8) = ov;
    }
}

__global__ __launch_bounds__(256) void prep_all(const float* __restrict__ X,
                                                const float* __restrict__ E,
                                                u16* __restrict__ Xh,
                                                u16* __restrict__ Eh,
                                                float* __restrict__ esq,
                                                double* __restrict__ esqd,
                                                int* __restrict__ fcnt) {
    const int tid = threadIdx.x;
    const int bid = blockIdx.x;
    if (bid < 2048) {
        transpose_slice(X, Xh, bid >> 5, (bid >> 3) & 3, bid & 7, tid);
    } else if (bid < 2080) {
        int b2 = bid - 2048;
        transpose_slice(E, Eh, 0, (b2 >> 3) & 3, b2 & 7, tid);
    } else {
        if (bid == 2080 && tid == 0) *fcnt = 0;
        int k = (bid - 2080) * 256 + tid;
        double s = 0.0;
#pragma unroll 8
        for (int c = 0; c < DCH; ++c) {
            double e = (double)E[c * KCB + k];
            s = fma(e, e, s);
        }
        esq[k] = (float)s;
        esqd[k] = s;
    }
}

// ---------------- main: fp16 MFMA distance, 128x128 tile, BK=32 (r5 geometry),
// integer-packed top-2 (32 regs) -> 3 blocks/CU via __launch_bounds__(256,3)
#define BUFS  16384
#define EH_O  8192
#define ESQ_O 32768
#define MRG_O 36864
#define SM_SZ 39936

__global__ __launch_bounds__(256, 3) void vq_main_mfma(
        const u16* __restrict__ XhG, const u16* __restrict__ EhG,
        const float* __restrict__ esq,
        int* __restrict__ idx_out, int* __restrict__ flag_cnt,
        int* __restrict__ flag_list) {
    __shared__ alignas(16) char sm[SM_SZ];
    const int tid = threadIdx.x;
    const int l = tid & 63;
    const int w = tid >> 6;
    const int wm = w >> 1, wn = w & 1;
    const int pbase = blockIdx.x * 128;

    // esq -> LDS (covered by prologue barrier)
    *reinterpret_cast<float4*>(sm + ESQ_O + tid * 16) =
        *reinterpret_cast<const float4*>(esq + tid * 4);

    const int rowt0 = w * 32 + (l >> 2);
    const int slog = (l & 3) ^ ((rowt0 >> 1) & 3);
    const char* XhB = reinterpret_cast<const char*>(XhG);
    const char* EhB = reinterpret_cast<const char*>(EhG);
    const size_t xoff0 = (size_t)(pbase + rowt0) * 512 + slog * 16;
    const size_t eoff0 = (size_t)rowt0 * 512 + slog * 16;
    const int w2k = (w * 2) * 1024;

    const int rA = wm * 64 + (l & 15);
    const int addrA = rA * 64 + (((l >> 4) ^ ((rA >> 1) & 3)) * 16);
    const int rB = wn * 64 + (l & 15);
    const int addrB = rB * 64 + (((l >> 4) ^ ((rB >> 1) & 3)) * 16);

    auto STAGE = [&](int bufo, int nt, int dt) {
        size_t xo = xoff0 + (size_t)dt * 64;
        gl_lds16(XhB + xo,        sm + bufo + w2k);
        gl_lds16(XhB + xo + 8192, sm + bufo + w2k + 1024);
        size_t eo = eoff0 + (size_t)nt * 65536 + (size_t)dt * 64;
        gl_lds16(EhB + eo,        sm + bufo + EH_O + w2k);
        gl_lds16(EhB + eo + 8192, sm + bufo + EH_O + w2k + 1024);
    };

    u32 b1[16], b2[16];
#pragma unroll
    for (int q = 0; q < 16; ++q) { b1[q] = 0xFFFFFFFFu; b2[q] = 0xFFFFFFFFu; }

    STAGE(0, 0, 0);
    __syncthreads();

    int step = 0;
    for (int nt = 0; nt < 8; ++nt) {
        f32x4 acc[4][4];
#pragma unroll
        for (int i = 0; i < 4; ++i)
#pragma unroll
            for (int j = 0; j < 4; ++j)
#pragma unroll
                for (int r = 0; r < 4; ++r) acc[i][j][r] = 0.f;

        for (int dt = 0; dt < 8; ++dt) {
            int nxt = step + 1;
            if (nxt < 64) STAGE((nxt & 1) * BUFS, nxt >> 3, nxt & 7);
            const char* bo = sm + (step & 1) * BUFS;
            f16x8 a[4], bh[4];
#pragma unroll
            for (int i = 0; i < 4; ++i)
                a[i] = *reinterpret_cast<const f16x8*>(bo + addrA + i * 1024);
#pragma unroll
            for (int j = 0; j < 4; ++j)
                bh[j] = *reinterpret_cast<const f16x8*>(bo + EH_O + addrB + j * 1024);
#pragma unroll
            for (int i = 0; i < 4; ++i)
#pragma unroll
                for (int j = 0; j < 4; ++j)
                    acc[i][j] = __builtin_amdgcn_mfma_f32_16x16x32_f16(a[i], bh[j], acc[i][j], 0, 0, 0);
            __syncthreads();
            ++step;
        }

        // epilogue: dist = esq - 2S in [0,512); key = (u32(dist*8192)<<10)|k
        // (order-preserving, quantum 2^-13 -> near-exact gap; k tiebreak = first idx)
        const int kb = nt * 128 + wn * 64 + (l & 15);
        float eq[4];
#pragma unroll
        for (int j = 0; j < 4; ++j)
            eq[j] = *reinterpret_cast<const float*>(sm + ESQ_O + (kb + j * 16) * 4);
#pragma unroll
        for (int i = 0; i < 4; ++i)
#pragma unroll
            for (int j = 0; j < 4; ++j)
#pragma unroll
                for (int r = 0; r < 4; ++r) {
                    float s = fmaf(-2.f, acc[i][j][r], eq[j]);
                    float qd = fminf(fmaxf(s, 0.f), 511.9f);
                    u32 v = (((u32)(qd * 8192.0f)) << 10) | (u32)(kb + j * 16);
                    int ri = i * 4 + r;
                    u32 m1 = umin2(b1[ri], v);
                    b2[ri] = umin2(b2[ri], umax2(b1[ri], v));
                    b1[ri] = m1;
                }
    }

    // cross-lane top-2 merge over the 16 k-col lanes
#pragma unroll
    for (int m = 1; m <= 8; m <<= 1) {
#pragma unroll
        for (int q = 0; q < 16; ++q) {
            u32 ob1 = (u32)__shfl_xor((int)b1[q], m);
            u32 ob2 = (u32)__shfl_xor((int)b2[q], m);
            u32 mx = umax2(b1[q], ob1);
            b1[q] = umin2(b1[q], ob1);
            b2[q] = umin2(umin2(b2[q], ob2), mx);
        }
    }

    if ((l & 15) == 0) {
#pragma unroll
        for (int i = 0; i < 4; ++i)
#pragma unroll
            for (int r = 0; r < 4; ++r) {
                int q = i * 4 + r;
                int rl = wm * 64 + i * 16 + (l >> 4) * 4 + r;
                *reinterpret_cast<u32*>(sm + MRG_O + (rl * 2 + wn) * 4) = b1[q];
                *reinterpret_cast<u32*>(sm + MRG_O + 1024 + (rl * 2 + wn) * 4) = b2[q];
            }
    }
    __syncthreads();
    if (tid < 128) {
        u32 a1 = *reinterpret_cast<u32*>(sm + MRG_O + (tid * 2 + 0) * 4);
        u32 a2 = *reinterpret_cast<u32*>(sm + MRG_O + 1024 + (tid * 2 + 0) * 4);
        u32 c1 = *reinterpret_cast<u32*>(sm + MRG_O + (tid * 2 + 1) * 4);
        u32 c2 = *reinterpret_cast<u32*>(sm + MRG_O + 1024 + (tid * 2 + 1) * 4);
        u32 P1 = umin2(a1, c1);
        u32 P2 = umin2(umin2(a2, c2), umax2(a1, c1));
        int n = pbase + tid;
        idx_out[n] = (int)(P1 & 1023u);
        if ((P2 >> 10) - (P1 >> 10) < (u32)GAPQ) {
            int s2 = atomicAdd(flag_cnt, 1);
            flag_list[s2] = n;
        }
    }
}

// ---------------- exact fp64 re-scan, 2 flags per block, 2048 blocks
#define RFPB 2
__global__ __launch_bounds__(256) void vq_repair(const float* __restrict__ X,
                                                 const float* __restrict__ E,
                                                 const double* __restrict__ esqd,
                                                 int* __restrict__ idx_out,
                                                 const int* __restrict__ flag_cnt,
                                                 const int* __restrict__ flag_list) {
    __shared__ double xs[RFPB][256];
    __shared__ double rd[RFPB][256];
    __shared__ int    ri[RFPB][256];
    const int tid = threadIdx.x;
    const int cnt = *flag_cnt;
    for (int f0 = blockIdx.x * RFPB; f0 < cnt; f0 += gridDim.x * RFPB) {
#pragma unroll
        for (int g = 0; g < RFPB; ++g) {
            int f = f0 + g;
            int n = flag_list[f < cnt ? f : f0];
            int b = n >> 10, p = n & 1023;
            xs[g][tid] = (double)X[(size_t)b * 262144 + (size_t)tid * 1024 + p];
        }
        __syncthreads();
        double s[RFPB][4];
#pragma unroll
        for (int g = 0; g < RFPB; ++g)
#pragma unroll
            for (int j = 0; j < 4; ++j) s[g][j] = 0.0;
        const float4* Erow = reinterpret_cast<const float4*>(E) + tid;   // E[c][tid*4]
#pragma unroll 2
        for (int c = 0; c < 256; ++c) {
            float4 ev = Erow[c * 256];
            double e0 = (double)ev.x, e1 = (double)ev.y, e2 = (double)ev.z, e3 = (double)ev.w;
#pragma unroll
            for (int g = 0; g < RFPB; ++g) {
                double xv = xs[g][c];
                s[g][0] = fma(xv, e0, s[g][0]);
                s[g][1] = fma(xv, e1, s[g][1]);
                s[g][2] = fma(xv, e2, s[g][2]);
                s[g][3] = fma(xv, e3, s[g][3]);
            }
        }
        const int k0 = tid * 4;
        const double eq0 = esqd[k0], eq1 = esqd[k0 + 1], eq2 = esqd[k0 + 2], eq3 = esqd[k0 + 3];
#pragma unroll
        for (int g = 0; g < RFPB; ++g) {
            double d0 = eq0 - 2.0 * s[g][0];
            double d1 = eq1 - 2.0 * s[g][1];
            double d2 = eq2 - 2.0 * s[g][2];
            double d3 = eq3 - 2.0 * s[g][3];
            double bd = d0; int bi = k0;
            if (d1 < bd) { bd = d1; bi = k0 + 1; }
            if (d2 < bd) { bd = d2; bi = k0 + 2; }
            if (d3 < bd) { bd = d3; bi = k0 + 3; }
            rd[g][tid] = bd; ri[g][tid] = bi;
        }
        __syncthreads();
        for (int off = 128; off > 0; off >>= 1) {
            if (tid < off) {
#pragma unroll
                for (int g = 0; g < RFPB; ++g) {
                    double od = rd[g][tid + off]; int oi = ri[g][tid + off];
                    if (od < rd[g][tid] || (od == rd[g][tid] && oi < ri[g][tid])) {
                        rd[g][tid] = od; ri[g][tid] = oi;
                    }
                }
            }
            __syncthreads();
        }
        if (tid < RFPB && (f0 + tid) < cnt) {
            idx_out[flag_list[f0 + tid]] = ri[tid][0];
        }
        __syncthreads();
    }
}

// ---------------- gather + write outputs (LDS-staged E slice, nt-stores)
#define WCC 8
__global__ __launch_bounds__(256) void vq_write(const float* __restrict__ E,
                                                const int* __restrict__ idx_ws,
                                                float* __restrict__ out0,
                                                float* __restrict__ out1,
                                                float* __restrict__ out2) {
    __shared__ float Es[WCC][1024];       // 32 KB
    const int tid = threadIdx.x;
    const int b   = blockIdx.x >> 5;      // 0..63
    const int cch = blockIdx.x & 31;      // 0..31 (8 c's each)
#pragma unroll
    for (int r = 0; r < 8; ++r) {
        int id4 = tid + 256 * r;          // float4 id over [8][256]
        int c = id4 >> 8;
        int q = id4 & 255;
        *reinterpret_cast<float4*>(&Es[c][q * 4]) =
            *reinterpret_cast<const float4*>(E + (size_t)(cch * WCC + c) * 1024 + q * 4);
    }
    int4 kv = *reinterpret_cast<const int4*>(idx_ws + b * 1024 + tid * 4);
    __syncthreads();
    if (cch == 0) {
        float4 v = {(float)kv.x, (float)kv.y, (float)kv.z, (float)kv.w};
        *reinterpret_cast<float4*>(out2 + b * 1024 + tid * 4) = v;
    }
#pragma unroll
    for (int c = 0; c < WCC; ++c) {
        f32x4 v = {Es[c][kv.x], Es[c][kv.y], Es[c][kv.z], Es[c][kv.w]};
        size_t o = (size_t)b * 262144 + (size_t)(cch * WCC + c) * 1024 + tid * 4;
        __builtin_nontemporal_store(v, reinterpret_cast<f32x4*>(out0 + o));
        __builtin_nontemporal_store(v, reinterpret_cast<f32x4*>(out1 + o));
    }
}

extern "C" void kernel_launch(void* const* d_in, const int* in_sizes, int n_in,
                              void* d_out, int out_size, void* d_ws, size_t ws_size,
                              hipStream_t stream) {
    const float* X = (const float*)d_in[0];   // [64,256,32,32] fp32
    const float* E = (const float*)d_in[1];   // [256,1024] fp32
    float* out = (float*)d_out;
    char* ws = (char*)d_ws;

    float* esq   = (float*)(ws + ESQ_WS);
    int* idx     = (int*)(ws + IDX_WS);
    int* fcnt    = (int*)(ws + FCNT_WS);
    int* flist   = (int*)(ws + FLIST_WS);
    double* esqd = (double*)(ws + ESQD_WS);
    u16* Xh      = (u16*)(ws + XH_WS);
    u16* Eh      = (u16*)(ws + EH_WS);

    prep_all<<<2084, 256, 0, stream>>>(X, E, Xh, Eh, esq, esqd, fcnt);
    vq_main_mfma<<<512, 256, 0, stream>>>(Xh, Eh, esq, idx, fcnt, flist);
    vq_repair<<<2048, 256, 0, stream>>>(X, E, esqd, idx, fcnt, flist);
    vq_write<<<2048, 256, 0, stream>>>(E, idx,
                                       out,                // q_ste
                                       out + 16777216,     // quantized
                                       out + 33554432);    // indices (as float)
}

// Round 18
// 151.140 us; speedup vs baseline: 1.2763x; 1.2763x over previous
//
#include <hip/hip_runtime.h>

typedef unsigned short u16;
typedef unsigned int   u32;

#define DCH  256
#define KCB  1024
#define HW   1024
#define NPOS 65536
#define MARGIN 0.07f

// ws layout (bytes)
#define ESQ_WS   0
#define IDX_WS   4096
#define FCNT_WS  266240
#define FLIST_WS 266304
#define ESQD_WS  528448ull             // double[1024] = 8 KB
#define XH_WS    1048576ull            // 65536*256 fp16 = 33.55 MB
#define EH_WS    34603008ull           // 1024*256 fp16 = 512 KB

using f32x4 = __attribute__((ext_vector_type(4))) float;
using f16x8 = __attribute__((ext_vector_type(8))) _Float16;

__device__ __forceinline__ u16 f2h(float x) {
    _Float16 h = (_Float16)x;
    return *reinterpret_cast<u16*>(&h);
}

__device__ __forceinline__ void gl_lds16(const void* g, void* l) {
    __builtin_amdgcn_global_load_lds(
        (const __attribute__((address_space(1))) void*)g,
        (__attribute__((address_space(3))) void*)l, 16, 0, 0);
}

// ---------------- fused prep: X transpose (2048 blocks) + E transpose (32) + esq (4)
__device__ __forceinline__ void transpose_slice(const float* __restrict__ src,
                                                u16* __restrict__ dst,
                                                int b, int pc, int cc, int tid) {
    __shared__ float Xs[32][260];     // pad 260 -> transpose reads conflict-free
    const int p0 = pc * 256;
    const int c0 = cc * 32;
    const size_t nbase = (size_t)b * 1024 + p0;
#pragma unroll
    for (int r = 0; r < 8; ++r) {
        int id4 = tid + 256 * r;            // float4 id over [32][64]
        int c = id4 >> 6;
        int q = id4 & 63;
        float4 v = *reinterpret_cast<const float4*>(
            src + (size_t)b * 262144 + (size_t)(c0 + c) * 1024 + p0 + q * 4);
        *reinterpret_cast<float4*>(&Xs[c][q * 4]) = v;
    }
    __syncthreads();
    const int p = tid;
#pragma unroll
    for (int dg = 0; dg < 4; ++dg) {
        u32 w0, w1, w2, w3;
        {
            float f0 = Xs[dg * 8 + 0][p], f1 = Xs[dg * 8 + 1][p];
            float f2 = Xs[dg * 8 + 2][p], f3 = Xs[dg * 8 + 3][p];
            float f4 = Xs[dg * 8 + 4][p], f5 = Xs[dg * 8 + 5][p];
            float f6 = Xs[dg * 8 + 6][p], f7 = Xs[dg * 8 + 7][p];
            w0 = (u32)f2h(f0) | ((u32)f2h(f1) << 16);
            w1 = (u32)f2h(f2) | ((u32)f2h(f3) << 16);
            w2 = (u32)f2h(f4) | ((u32)f2h(f5) << 16);
            w3 = (u32)f2h(f6) | ((u32)f2h(f7) << 16);
        }
        uint4 ov = {w0, w1, w2, w3};
        *reinterpret_cast<uint4*>(dst + (nbase + p) * 256 + c0 + dg * 8) = ov;
    }
}

__global__ __launch_bounds__(256) void prep_all(const float* __restrict__ X,
                                                const float* __restrict__ E,
                                                u16* __restrict__ Xh,
                                                u16* __restrict__ Eh,
                                                float* __restrict__ esq,
                                                double* __restrict__ esqd,
                                                int* __restrict__ fcnt) {
    const int tid = threadIdx.x;
    const int bid = blockIdx.x;
    if (bid < 2048) {
        transpose_slice(X, Xh, bid >> 5, (bid >> 3) & 3, bid & 7, tid);
    } else if (bid < 2080) {
        int b2 = bid - 2048;
        transpose_slice(E, Eh, 0, (b2 >> 3) & 3, b2 & 7, tid);
    } else {
        if (bid == 2080 && tid == 0) *fcnt = 0;
        int k = (bid - 2080) * 256 + tid;
        double s = 0.0;
#pragma unroll 8
        for (int c = 0; c < DCH; ++c) {
            double e = (double)E[c * KCB + k];
            s = fma(e, e, s);
        }
        esq[k] = (float)s;
        esqd[k] = s;
    }
}

// ---------------- main: fp16 MFMA distance, 128x128 tile, BK=64 (32 MFMA/barrier)
#define BUFS  32768
#define EB_O  16384
#define ESQ_O 65536
#define MRG_O 69632
#define SM_SZ 72704

__global__ __launch_bounds__(256, 2) void vq_main_mfma(
        const u16* __restrict__ XhG, const u16* __restrict__ EhG,
        const float* __restrict__ esq,
        int* __restrict__ idx_out, int* __restrict__ flag_cnt,
        int* __restrict__ flag_list) {
    __shared__ alignas(16) char sm[SM_SZ];
    const int tid = threadIdx.x;
    const int l = tid & 63;
    const int w = tid >> 6;
    const int wm = w >> 1, wn = w & 1;
    const int pbase = blockIdx.x * 128;

    // esq -> LDS (covered by prologue barrier)
    *reinterpret_cast<float4*>(sm + ESQ_O + tid * 16) =
        *reinterpret_cast<const float4*>(esq + tid * 4);

    // staging: instr k covers rows w*32 + k*8 + (l>>3), LDS slot l&7,
    // global slot = (l&7) ^ (row&7) = (l&7) ^ (l>>3)
    const int srow = w * 32 + (l >> 3);
    const int sswz = ((l & 7) ^ (l >> 3)) * 16;
    const char* XhB = reinterpret_cast<const char*>(XhG);
    const char* EhB = reinterpret_cast<const char*>(EhG);
    const size_t xbase = (size_t)(pbase + srow) * 512 + sswz;
    const size_t ebase = (size_t)srow * 512 + sswz;

    // fragment read addrs: row rA = wm*64 + (l&15) (+i*16), slot = (ds*4+(l>>4)) ^ (l&7)
    const int sA0 = (((l >> 4) ^ (l & 7))) * 16;        // ds=0 slot byte
    const int addrA0 = wm * 8192 + (l & 15) * 128 + sA0;
    const int addrB0 = wn * 8192 + (l & 15) * 128 + sA0;

    auto STAGE = [&](int bufo, int nt, int kt) {
        const size_t xo = xbase + (size_t)kt * 128;
        const size_t eo = ebase + (size_t)nt * 65536 + (size_t)kt * 128;
#pragma unroll
        for (int k = 0; k < 4; ++k) {
            gl_lds16(XhB + xo + k * 4096, sm + bufo + (w * 4 + k) * 1024);
            gl_lds16(EhB + eo + k * 4096, sm + bufo + EB_O + (w * 4 + k) * 1024);
        }
    };

    float b1[16], b2[16];
    int   i1[16];
#pragma unroll
    for (int q = 0; q < 16; ++q) { b1[q] = 3.4e38f; b2[q] = 3.4e38f; i1[q] = 0; }

    STAGE(0, 0, 0);
    __syncthreads();

    int step = 0;
    for (int nt = 0; nt < 8; ++nt) {
        f32x4 acc[4][4];
#pragma unroll
        for (int i = 0; i < 4; ++i)
#pragma unroll
            for (int j = 0; j < 4; ++j)
#pragma unroll
                for (int r = 0; r < 4; ++r) acc[i][j][r] = 0.f;

        for (int kt = 0; kt < 4; ++kt) {
            int nxt = step + 1;
            if (nxt < 32) STAGE((nxt & 1) * BUFS, nxt >> 2, nxt & 3);
            const char* bo = sm + (step & 1) * BUFS;
#pragma unroll
            for (int ds = 0; ds < 2; ++ds) {
                const int so = ds * 64;        // slot term flips bit2: ^64 bytes
                f16x8 a[4], bh[4];
#pragma unroll
                for (int i = 0; i < 4; ++i)
                    a[i] = *reinterpret_cast<const f16x8*>(bo + ((addrA0 ^ so) + i * 2048));
#pragma unroll
                for (int j = 0; j < 4; ++j)
                    bh[j] = *reinterpret_cast<const f16x8*>(bo + EB_O + ((addrB0 ^ so) + j * 2048));
#pragma unroll
                for (int i = 0; i < 4; ++i)
#pragma unroll
                    for (int j = 0; j < 4; ++j)
                        acc[i][j] = __builtin_amdgcn_mfma_f32_16x16x32_f16(a[i], bh[j], acc[i][j], 0, 0, 0);
            }
            __syncthreads();
            ++step;
        }

        // epilogue: dist = esq - 2S, exact fp32 running top-2 + index
        const int kb = nt * 128 + wn * 64 + (l & 15);
        float eq[4];
#pragma unroll
        for (int j = 0; j < 4; ++j)
            eq[j] = *reinterpret_cast<const float*>(sm + ESQ_O + (kb + j * 16) * 4);
#pragma unroll
        for (int i = 0; i < 4; ++i)
#pragma unroll
            for (int j = 0; j < 4; ++j)
#pragma unroll
                for (int r = 0; r < 4; ++r) {
                    float s = fmaf(-2.f, acc[i][j][r], eq[j]);
                    int ri = i * 4 + r;
                    bool lt = s < b1[ri];
                    b2[ri] = fminf(b2[ri], fmaxf(s, b1[ri]));
                    i1[ri] = lt ? (kb + j * 16) : i1[ri];
                    b1[ri] = fminf(b1[ri], s);
                }
    }

    // cross-lane top-2 merge over the 16 k-col lanes
#pragma unroll
    for (int m = 1; m <= 8; m <<= 1) {
#pragma unroll
        for (int q = 0; q < 16; ++q) {
            float ob1 = __shfl_xor(b1[q], m);
            float ob2 = __shfl_xor(b2[q], m);
            int   oi  = __shfl_xor(i1[q], m);
            bool lt = ob1 < b1[q];
            b2[q] = fminf(fminf(b2[q], ob2), fmaxf(b1[q], ob1));
            i1[q] = lt ? oi : i1[q];
            b1[q] = fminf(b1[q], ob1);
        }
    }

    if ((l & 15) == 0) {
#pragma unroll
        for (int i = 0; i < 4; ++i)
#pragma unroll
            for (int r = 0; r < 4; ++r) {
                int q = i * 4 + r;
                int rl = wm * 64 + i * 16 + (l >> 4) * 4 + r;
                *reinterpret_cast<float*>(sm + MRG_O + (rl * 2 + wn) * 4) = b1[q];
                *reinterpret_cast<float*>(sm + MRG_O + 1024 + (rl * 2 + wn) * 4) = b2[q];
                *reinterpret_cast<int*>(sm + MRG_O + 2048 + (rl * 2 + wn) * 4) = i1[q];
            }
    }
    __syncthreads();
    if (tid < 128) {
        float a1 = *reinterpret_cast<float*>(sm + MRG_O + (tid * 2 + 0) * 4);
        float a2 = *reinterpret_cast<float*>(sm + MRG_O + 1024 + (tid * 2 + 0) * 4);
        int   ai = *reinterpret_cast<int*>(sm + MRG_O + 2048 + (tid * 2 + 0) * 4);
        float c1 = *reinterpret_cast<float*>(sm + MRG_O + (tid * 2 + 1) * 4);
        float c2 = *reinterpret_cast<float*>(sm + MRG_O + 1024 + (tid * 2 + 1) * 4);
        int   ci = *reinterpret_cast<int*>(sm + MRG_O + 2048 + (tid * 2 + 1) * 4);
        bool lt = c1 < a1;
        float B1 = fminf(a1, c1);
        float B2 = fminf(fminf(a2, c2), fmaxf(a1, c1));
        int I1 = lt ? ci : ai;
        int n = pbase + tid;
        idx_out[n] = I1;
        if (B2 - B1 < MARGIN) {
            int s2 = atomicAdd(flag_cnt, 1);
            flag_list[s2] = n;
        }
    }
}

// ---------------- exact fp64 re-scan, 2 flags per block, 2048 blocks
#define RFPB 2
__global__ __launch_bounds__(256) void vq_repair(const float* __restrict__ X,
                                                 const float* __restrict__ E,
                                                 const double* __restrict__ esqd,
                                                 int* __restrict__ idx_out,
                                                 const int* __restrict__ flag_cnt,
                                                 const int* __restrict__ flag_list) {
    __shared__ double xs[RFPB][256];
    __shared__ double rd[RFPB][256];
    __shared__ int    ri[RFPB][256];
    const int tid = threadIdx.x;
    const int cnt = *flag_cnt;
    for (int f0 = blockIdx.x * RFPB; f0 < cnt; f0 += gridDim.x * RFPB) {
#pragma unroll
        for (int g = 0; g < RFPB; ++g) {
            int f = f0 + g;
            int n = flag_list[f < cnt ? f : f0];
            int b = n >> 10, p = n & 1023;
            xs[g][tid] = (double)X[(size_t)b * 262144 + (size_t)tid * 1024 + p];
        }
        __syncthreads();
        double s[RFPB][4];
#pragma unroll
        for (int g = 0; g < RFPB; ++g)
#pragma unroll
            for (int j = 0; j < 4; ++j) s[g][j] = 0.0;
        const float4* Erow = reinterpret_cast<const float4*>(E) + tid;   // E[c][tid*4]
#pragma unroll 2
        for (int c = 0; c < 256; ++c) {
            float4 ev = Erow[c * 256];
            double e0 = (double)ev.x, e1 = (double)ev.y, e2 = (double)ev.z, e3 = (double)ev.w;
#pragma unroll
            for (int g = 0; g < RFPB; ++g) {
                double xv = xs[g][c];
                s[g][0] = fma(xv, e0, s[g][0]);
                s[g][1] = fma(xv, e1, s[g][1]);
                s[g][2] = fma(xv, e2, s[g][2]);
                s[g][3] = fma(xv, e3, s[g][3]);
            }
        }
        const int k0 = tid * 4;
        const double eq0 = esqd[k0], eq1 = esqd[k0 + 1], eq2 = esqd[k0 + 2], eq3 = esqd[k0 + 3];
#pragma unroll
        for (int g = 0; g < RFPB; ++g) {
            double d0 = eq0 - 2.0 * s[g][0];
            double d1 = eq1 - 2.0 * s[g][1];
            double d2 = eq2 - 2.0 * s[g][2];
            double d3 = eq3 - 2.0 * s[g][3];
            double bd = d0; int bi = k0;
            if (d1 < bd) { bd = d1; bi = k0 + 1; }
            if (d2 < bd) { bd = d2; bi = k0 + 2; }
            if (d3 < bd) { bd = d3; bi = k0 + 3; }
            rd[g][tid] = bd; ri[g][tid] = bi;
        }
        __syncthreads();
        for (int off = 128; off > 0; off >>= 1) {
            if (tid < off) {
#pragma unroll
                for (int g = 0; g < RFPB; ++g) {
                    double od = rd[g][tid + off]; int oi = ri[g][tid + off];
                    if (od < rd[g][tid] || (od == rd[g][tid] && oi < ri[g][tid])) {
                        rd[g][tid] = od; ri[g][tid] = oi;
                    }
                }
            }
            __syncthreads();
        }
        if (tid < RFPB && (f0 + tid) < cnt) {
            idx_out[flag_list[f0 + tid]] = ri[tid][0];
        }
        __syncthreads();
    }
}

// ---------------- gather + write outputs (LDS-staged E slice, coalesced)
#define WCC 8
__global__ __launch_bounds__(256) void vq_write(const float* __restrict__ E,
                                                const int* __restrict__ idx_ws,
                                                float* __restrict__ out0,
                                                float* __restrict__ out1,
                                                float* __restrict__ out2) {
    __shared__ float Es[WCC][1024];       // 32 KB
    const int tid = threadIdx.x;
    const int b   = blockIdx.x >> 5;      // 0..63
    const int cch = blockIdx.x & 31;      // 0..31 (8 c's each)
#pragma unroll
    for (int r = 0; r < 8; ++r) {
        int id4 = tid + 256 * r;          // float4 id over [8][256]
        int c = id4 >> 8;
        int q = id4 & 255;
        *reinterpret_cast<float4*>(&Es[c][q * 4]) =
            *reinterpret_cast<const float4*>(E + (size_t)(cch * WCC + c) * 1024 + q * 4);
    }
    int4 kv = *reinterpret_cast<const int4*>(idx_ws + b * 1024 + tid * 4);
    __syncthreads();
    if (cch == 0) {
        float4 v = {(float)kv.x, (float)kv.y, (float)kv.z, (float)kv.w};
        *reinterpret_cast<float4*>(out2 + b * 1024 + tid * 4) = v;
    }
#pragma unroll
    for (int c = 0; c < WCC; ++c) {
        float4 v = {Es[c][kv.x], Es[c][kv.y], Es[c][kv.z], Es[c][kv.w]};
        size_t o = (size_t)b * 262144 + (size_t)(cch * WCC + c) * 1024 + tid * 4;
        *reinterpret_cast<float4*>(out0 + o) = v;
        *reinterpret_cast<float4*>(out1 + o) = v;
    }
}

extern "C" void kernel_launch(void* const* d_in, const int* in_sizes, int n_in,
                              void* d_out, int out_size, void* d_ws, size_t ws_size,
                              hipStream_t stream) {
    const float* X = (const float*)d_in[0];   // [64,256,32,32] fp32
    const float* E = (const float*)d_in[1];   // [256,1024] fp32
    float* out = (float*)d_out;
    char* ws = (char*)d_ws;

    float* esq   = (float*)(ws + ESQ_WS);
    int* idx     = (int*)(ws + IDX_WS);
    int* fcnt    = (int*)(ws + FCNT_WS);
    int* flist   = (int*)(ws + FLIST_WS);
    double* esqd = (double*)(ws + ESQD_WS);
    u16* Xh      = (u16*)(ws + XH_WS);
    u16* Eh      = (u16*)(ws + EH_WS);

    prep_all<<<2084, 256, 0, stream>>>(X, E, Xh, Eh, esq, esqd, fcnt);
    vq_main_mfma<<<512, 256, 0, stream>>>(Xh, Eh, esq, idx, fcnt, flist);
    vq_repair<<<2048, 256, 0, stream>>>(X, E, esqd, idx, fcnt, flist);
    vq_write<<<2048, 256, 0, stream>>>(E, idx,
                                       out,                // q_ste
                                       out + 16777216,     // quantized
                                       out + 33554432);    // indices (as float)
}